// Round 2
// baseline (859.441 us; speedup 1.0000x reference)
//
#include <hip/hip_runtime.h>
#include <hip/hip_bf16.h>

typedef __bf16 bf16x8 __attribute__((ext_vector_type(8)));
typedef float  f32x4  __attribute__((ext_vector_type(4)));

// ---------------- preprocessing kernels ----------------

__global__ void degree_kernel(const int* __restrict__ dst, int* __restrict__ deg, int E) {
    int e = blockIdx.x * blockDim.x + threadIdx.x;
    if (e < E) atomicAdd(&deg[dst[e]], 1);
}

// single-block exclusive scan over deg[0..n) -> offsets[0..n] (+ cursor copy)
// wave-shuffle scan: 3 barriers per 1024-chunk instead of 20.
__global__ void scan_kernel(const int* __restrict__ deg, int* __restrict__ offsets,
                            int* __restrict__ cursor, int n) {
    __shared__ int wsum[16];
    __shared__ int carry_s;
    if (threadIdx.x == 0) carry_s = 0;
    __syncthreads();
    int lane = threadIdx.x & 63;
    int wave = threadIdx.x >> 6;
    for (int base = 0; base < n; base += 1024) {
        int i = base + threadIdx.x;
        int v = (i < n) ? deg[i] : 0;
        // per-wave inclusive scan
        int s = v;
#pragma unroll
        for (int off = 1; off < 64; off <<= 1) {
            int t = __shfl_up(s, off, 64);
            if (lane >= off) s += t;
        }
        if (lane == 63) wsum[wave] = s;
        __syncthreads();
        if (wave == 0 && lane < 16) {
            int ws = wsum[lane];
            int ss = ws;
#pragma unroll
            for (int off = 1; off < 16; off <<= 1) {
                int t = __shfl_up(ss, off, 64);
                if (lane >= off) ss += t;
            }
            wsum[lane] = ss - ws;  // exclusive wave prefix
        }
        __syncthreads();
        int excl = (s - v) + wsum[wave];
        int carry = carry_s;
        if (i < n) { offsets[i] = carry + excl; cursor[i] = carry + excl; }
        __syncthreads();           // everyone read carry_s before update
        if (threadIdx.x == 1023) carry_s = carry + excl + v;  // chunk total
        __syncthreads();
    }
    if (threadIdx.x == 0) offsets[n] = carry_s;
}

__global__ void scatter_kernel(const int* __restrict__ src, const int* __restrict__ dst,
                               int* __restrict__ cursor, int* __restrict__ sorted_src, int E) {
    int e = blockIdx.x * blockDim.x + threadIdx.x;
    if (e < E) {
        int d = dst[e];
        int pos = atomicAdd(&cursor[d], 1);
        sorted_src[pos] = src[e];
    }
}

// graph boundaries: batch_index sorted; gstart[g] = lower_bound(batch, g), g in [0..G]
__global__ void bounds_kernel(const int* __restrict__ batch, int* __restrict__ gstart,
                              int N, int G) {
    int g = blockIdx.x * blockDim.x + threadIdx.x;
    if (g <= G) {
        int lo = 0, hi = N;
        while (lo < hi) {
            int mid = (lo + hi) >> 1;
            if (batch[mid] < g) lo = mid + 1; else hi = mid;
        }
        gstart[g] = lo;
    }
}

__global__ void cvt_f32_to_bf16(const float* __restrict__ in,
                                __hip_bfloat16* __restrict__ out, int n) {
    int i = blockIdx.x * blockDim.x + threadIdx.x;
    if (i < n) out[i] = __float2bfloat16(in[i]);
}

// Wcat[j][k] = (k<128 ? Wroot[j][k] : Wrel[j][k-128]) as bf16 ; Wcat is [128][256]
__global__ void build_wcat(const float* __restrict__ Wr, const float* __restrict__ Wn,
                           __hip_bfloat16* __restrict__ Wcat) {
    int idx = blockIdx.x * blockDim.x + threadIdx.x;
    if (idx < 128 * 256) {
        int j = idx >> 8, k = idx & 255;
        float v = (k < 128) ? Wr[j * 128 + k] : Wn[j * 128 + (k - 128)];
        Wcat[idx] = __float2bfloat16(v);
    }
}

// ---------------- per-layer kernels ----------------

// agg[i][f] = sum over CSR neighbors of h[nb][f]; 128 threads per node (1 feature each)
__global__ void agg_kernel(const __hip_bfloat16* __restrict__ h,
                           const int* __restrict__ offsets,
                           const int* __restrict__ sorted_src,
                           __hip_bfloat16* __restrict__ agg, int N) {
    int node = blockIdx.x * (blockDim.x >> 7) + (threadIdx.x >> 7);
    int f = threadIdx.x & 127;
    if (node >= N) return;
    int s = offsets[node], e = offsets[node + 1];
    float acc = 0.f;
    for (int t = s; t < e; ++t) {
        int nb = sorted_src[t];
        acc += __bfloat162float(h[nb * 128 + f]);
    }
    agg[node * 128 + f] = __float2bfloat16(acc);
}

// out = gelu( [h | agg] @ Wcat^T + b ), M=N rows, N=128 cols, K=256
// block = 256 threads = 4 waves; block tile = 64 rows; wave w -> rows [w*16, w*16+16)
__global__ void gemm_layer_kernel(const __hip_bfloat16* __restrict__ h,
                                  const __hip_bfloat16* __restrict__ agg,
                                  const __hip_bfloat16* __restrict__ Wcat,  // [128][256]
                                  const float* __restrict__ bias,           // [128]
                                  __hip_bfloat16* __restrict__ out, int N) {
    int wave = threadIdx.x >> 6;
    int lane = threadIdx.x & 63;
    int row0 = blockIdx.x * 64 + wave * 16;
    if (row0 >= N) return;

    int la  = lane & 15;          // A-row / B-col within 16-tile
    int ke0 = (lane >> 4) * 8;    // k element offset within 32-chunk

    f32x4 acc[8] = {};

    for (int ks = 0; ks < 8; ++ks) {
        int k = ks * 32 + ke0;    // 0..255 (uniform side of the 128 split per ks)
        const __hip_bfloat16* ap = (k < 128) ? &h[(size_t)(row0 + la) * 128 + k]
                                             : &agg[(size_t)(row0 + la) * 128 + (k - 128)];
        bf16x8 a = *reinterpret_cast<const bf16x8*>(ap);
#pragma unroll
        for (int n = 0; n < 8; ++n) {
            bf16x8 b = *reinterpret_cast<const bf16x8*>(&Wcat[(n * 16 + la) * 256 + k]);
            acc[n] = __builtin_amdgcn_mfma_f32_16x16x32_bf16(a, b, acc[n], 0, 0, 0);
        }
    }

    // D layout (m89-verified): col = lane&15, row = (lane>>4)*4 + j
    int orow = row0 + (lane >> 4) * 4;
#pragma unroll
    for (int n = 0; n < 8; ++n) {
        int col = n * 16 + la;
        float bv = bias[col];
#pragma unroll
        for (int j = 0; j < 4; ++j) {
            float xv = acc[n][j] + bv;
            float g = 0.5f * xv * (1.0f + erff(xv * 0.70710678118654752f));
            out[(size_t)(orow + j) * 128 + col] = __float2bfloat16(g);
        }
    }
}

// one block per graph: mean-pool over its node range fused with @ Wout.T + bout
__global__ void pool_out_kernel(const __hip_bfloat16* __restrict__ h,
                                const int* __restrict__ gstart,
                                const float* __restrict__ Wout,
                                const float* __restrict__ bout,
                                float* __restrict__ out) {
    int g = blockIdx.x;
    int f = threadIdx.x;  // 128
    int s = gstart[g], e = gstart[g + 1];
    float acc = 0.f;
    for (int i = s; i < e; ++i) acc += __bfloat162float(h[(size_t)i * 128 + f]);
    float v = acc * Wout[f];
    __shared__ float red[128];
    red[f] = v;
    __syncthreads();
    for (int off = 64; off > 0; off >>= 1) {
        if (f < off) red[f] += red[f + off];
        __syncthreads();
    }
    if (f == 0) {
        float cnt = (float)(e - s);
        out[g] = red[0] / fmaxf(cnt, 1.0f) + bout[0];
    }
}

// ---------------- launch ----------------

extern "C" void kernel_launch(void* const* d_in, const int* in_sizes, int n_in,
                              void* d_out, int out_size, void* d_ws, size_t ws_size,
                              hipStream_t stream) {
    const float* x          = (const float*)d_in[0];
    const int*   edge_index = (const int*)d_in[1];
    const int*   batch      = (const int*)d_in[2];
    const float* Wroot[4] = {(const float*)d_in[3], (const float*)d_in[6],
                             (const float*)d_in[9], (const float*)d_in[12]};
    const float* Wrel[4]  = {(const float*)d_in[4], (const float*)d_in[7],
                             (const float*)d_in[10], (const float*)d_in[13]};
    const float* bias[4]  = {(const float*)d_in[5], (const float*)d_in[8],
                             (const float*)d_in[11], (const float*)d_in[14]};
    const float* Wout = (const float*)d_in[15];
    const float* bout = (const float*)d_in[16];
    float* out = (float*)d_out;

    const int N = in_sizes[2];       // 40000
    const int E = in_sizes[1] / 2;   // 640000
    const int G = 128;
    const int* src = edge_index;
    const int* dst = edge_index + E;

    char* ws = (char*)d_ws;
    size_t o = 0;
    auto alloc = [&](size_t bytes) { void* p = ws + o; o += (bytes + 255) & ~(size_t)255; return p; };

    __hip_bfloat16* hx   = (__hip_bfloat16*)alloc((size_t)N * 128 * 2);
    __hip_bfloat16* hb0  = (__hip_bfloat16*)alloc((size_t)N * 128 * 2);
    __hip_bfloat16* hb1  = (__hip_bfloat16*)alloc((size_t)N * 128 * 2);
    __hip_bfloat16* agg  = (__hip_bfloat16*)alloc((size_t)N * 128 * 2);
    __hip_bfloat16* wcat[4];
    for (int l = 0; l < 4; ++l) wcat[l] = (__hip_bfloat16*)alloc(128 * 256 * 2);
    int* deg     = (int*)alloc((size_t)N * 4);
    int* offsets = (int*)alloc((size_t)(N + 1) * 4);
    int* cursor  = (int*)alloc((size_t)N * 4);
    int* sorted  = (int*)alloc((size_t)E * 4);
    int* gstart  = (int*)alloc((size_t)(G + 1) * 4);

    // CSR build (reused by all 4 layers)
    hipMemsetAsync(deg, 0, (size_t)N * 4, stream);
    degree_kernel<<<(E + 255) / 256, 256, 0, stream>>>(dst, deg, E);
    scan_kernel<<<1, 1024, 0, stream>>>(deg, offsets, cursor, N);
    scatter_kernel<<<(E + 255) / 256, 256, 0, stream>>>(src, dst, cursor, sorted, E);
    bounds_kernel<<<1, 256, 0, stream>>>(batch, gstart, N, G);

    // input & weight conversion to bf16
    cvt_f32_to_bf16<<<(N * 128 + 255) / 256, 256, 0, stream>>>(x, hx, N * 128);
    for (int l = 0; l < 4; ++l)
        build_wcat<<<(128 * 256 + 255) / 256, 256, 0, stream>>>(Wroot[l], Wrel[l], wcat[l]);

    // 4 GraphConv + gelu layers
    __hip_bfloat16* hin = hx;
    __hip_bfloat16* houts[4] = {hb0, hb1, hb0, hb1};
    for (int l = 0; l < 4; ++l) {
        agg_kernel<<<N / 2, 256, 0, stream>>>(hin, offsets, sorted, agg, N);
        gemm_layer_kernel<<<(N + 63) / 64, 256, 0, stream>>>(hin, agg, wcat[l], bias[l], houts[l], N);
        hin = houts[l];
    }

    // mean pool + output head
    pool_out_kernel<<<G, 128, 0, stream>>>(hin, gstart, Wout, bout, out);
}

// Round 4
// 493.148 us; speedup vs baseline: 1.7428x; 1.7428x over previous
//
#include <hip/hip_runtime.h>
#include <hip/hip_bf16.h>

typedef __bf16 bf16x8 __attribute__((ext_vector_type(8)));
typedef float  f32x4  __attribute__((ext_vector_type(4)));

__device__ __forceinline__ float bf16lo(unsigned v) { return __uint_as_float(v << 16); }
__device__ __forceinline__ float bf16hi(unsigned v) { return __uint_as_float(v & 0xffff0000u); }

// ---------------- preprocessing kernels ----------------

__global__ void degree_kernel(const int* __restrict__ dst, int* __restrict__ deg, int E) {
    int e = blockIdx.x * blockDim.x + threadIdx.x;
    if (e < E) atomicAdd(&deg[dst[e]], 1);
}

// single-block exclusive scan over deg[0..n) -> offsets[0..n] (+ cursor copy)
__global__ void scan_kernel(const int* __restrict__ deg, int* __restrict__ offsets,
                            int* __restrict__ cursor, int n) {
    __shared__ int wsum[16];
    __shared__ int carry_s;
    if (threadIdx.x == 0) carry_s = 0;
    __syncthreads();
    int lane = threadIdx.x & 63;
    int wave = threadIdx.x >> 6;
    for (int base = 0; base < n; base += 1024) {
        int i = base + threadIdx.x;
        int v = (i < n) ? deg[i] : 0;
        int s = v;
#pragma unroll
        for (int off = 1; off < 64; off <<= 1) {
            int t = __shfl_up(s, off, 64);
            if (lane >= off) s += t;
        }
        if (lane == 63) wsum[wave] = s;
        __syncthreads();
        if (wave == 0 && lane < 16) {
            int ws = wsum[lane];
            int ss = ws;
#pragma unroll
            for (int off = 1; off < 16; off <<= 1) {
                int t = __shfl_up(ss, off, 64);
                if (lane >= off) ss += t;
            }
            wsum[lane] = ss - ws;
        }
        __syncthreads();
        int excl = (s - v) + wsum[wave];
        int carry = carry_s;
        if (i < n) { offsets[i] = carry + excl; cursor[i] = carry + excl; }
        __syncthreads();
        if (threadIdx.x == 1023) carry_s = carry + excl + v;
        __syncthreads();
    }
    if (threadIdx.x == 0) offsets[n] = carry_s;
}

__global__ void scatter_kernel(const int* __restrict__ src, const int* __restrict__ dst,
                               int* __restrict__ cursor, int* __restrict__ sorted_src, int E) {
    int e = blockIdx.x * blockDim.x + threadIdx.x;
    if (e < E) {
        int d = dst[e];
        int pos = atomicAdd(&cursor[d], 1);
        sorted_src[pos] = src[e];
    }
}

__global__ void bounds_kernel(const int* __restrict__ batch, int* __restrict__ gstart,
                              int N, int G) {
    int g = blockIdx.x * blockDim.x + threadIdx.x;
    if (g <= G) {
        int lo = 0, hi = N;
        while (lo < hi) {
            int mid = (lo + hi) >> 1;
            if (batch[mid] < g) lo = mid + 1; else hi = mid;
        }
        gstart[g] = lo;
    }
}

__global__ void cvt_f32_to_bf16(const float* __restrict__ in,
                                __hip_bfloat16* __restrict__ out, int n) {
    int i = blockIdx.x * blockDim.x + threadIdx.x;
    if (i < n) out[i] = __float2bfloat16(in[i]);
}

__global__ void build_wcat(const float* __restrict__ Wr, const float* __restrict__ Wn,
                           __hip_bfloat16* __restrict__ Wcat) {
    int idx = blockIdx.x * blockDim.x + threadIdx.x;
    if (idx < 128 * 256) {
        int j = idx >> 8, k = idx & 255;
        float v = (k < 128) ? Wr[j * 128 + k] : Wn[j * 128 + (k - 128)];
        Wcat[idx] = __float2bfloat16(v);
    }
}

// ---------------- per-layer kernels ----------------

// 1 wave per node; lane owns features [2*lane, 2*lane+1] (4B). Unroll x4 -> 4
// independent gathers in flight per wave (latency-bound fix).
__global__ void agg_kernel(const __hip_bfloat16* __restrict__ h,
                           const int* __restrict__ offsets,
                           const int* __restrict__ sorted_src,
                           __hip_bfloat16* __restrict__ agg, int N) {
    int node = blockIdx.x * (blockDim.x >> 6) + (threadIdx.x >> 6);
    int lane = threadIdx.x & 63;
    if (node >= N) return;
    int s = offsets[node], e = offsets[node + 1];
    const unsigned* hu = (const unsigned*)h;
    float a0x = 0.f, a0y = 0.f, a1x = 0.f, a1y = 0.f;
    float a2x = 0.f, a2y = 0.f, a3x = 0.f, a3y = 0.f;
    int t = s;
    for (; t + 4 <= e; t += 4) {
        int n0 = sorted_src[t];
        int n1 = sorted_src[t + 1];
        int n2 = sorted_src[t + 2];
        int n3 = sorted_src[t + 3];
        unsigned v0 = hu[(size_t)n0 * 64 + lane];
        unsigned v1 = hu[(size_t)n1 * 64 + lane];
        unsigned v2 = hu[(size_t)n2 * 64 + lane];
        unsigned v3 = hu[(size_t)n3 * 64 + lane];
        a0x += bf16lo(v0); a0y += bf16hi(v0);
        a1x += bf16lo(v1); a1y += bf16hi(v1);
        a2x += bf16lo(v2); a2y += bf16hi(v2);
        a3x += bf16lo(v3); a3y += bf16hi(v3);
    }
    for (; t < e; ++t) {
        int nb = sorted_src[t];
        unsigned v = hu[(size_t)nb * 64 + lane];
        a0x += bf16lo(v); a0y += bf16hi(v);
    }
    float sx = (a0x + a1x) + (a2x + a3x);
    float sy = (a0y + a1y) + (a2y + a3y);
    __hip_bfloat162 o;
    o.x = __float2bfloat16(sx);
    o.y = __float2bfloat16(sy);
    *reinterpret_cast<__hip_bfloat162*>(&agg[(size_t)node * 128 + lane * 2]) = o;
}

// out = gelu( [h | agg] @ Wcat^T + b ): wave computes 32 rows x 128 cols,
// two A-frags share each B-load. Block = 4 waves = 128 rows.
__global__ void gemm_layer_kernel(const __hip_bfloat16* __restrict__ h,
                                  const __hip_bfloat16* __restrict__ agg,
                                  const __hip_bfloat16* __restrict__ Wcat,  // [128][256]
                                  const float* __restrict__ bias,           // [128]
                                  __hip_bfloat16* __restrict__ out, int N) {
    int wave = threadIdx.x >> 6;
    int lane = threadIdx.x & 63;
    int row0 = blockIdx.x * 128 + wave * 32;
    if (row0 >= N) return;

    int la  = lane & 15;          // A-row / B-col within 16-tile
    int ke0 = (lane >> 4) * 8;    // k element offset within 32-chunk

    int rA0 = row0 + la;       if (rA0 >= N) rA0 = N - 1;
    int rA1 = row0 + 16 + la;  if (rA1 >= N) rA1 = N - 1;

    f32x4 acc0[8] = {};
    f32x4 acc1[8] = {};

#pragma unroll
    for (int ks = 0; ks < 8; ++ks) {
        int k = ks * 32 + ke0;    // 0..255; k<128 -> h, else agg (uniform per ks)
        const __hip_bfloat16* base = (k < 128) ? h : agg;
        int kk = (k < 128) ? k : (k - 128);
        bf16x8 a0 = *reinterpret_cast<const bf16x8*>(&base[(size_t)rA0 * 128 + kk]);
        bf16x8 a1 = *reinterpret_cast<const bf16x8*>(&base[(size_t)rA1 * 128 + kk]);
#pragma unroll
        for (int n = 0; n < 8; ++n) {
            bf16x8 b = *reinterpret_cast<const bf16x8*>(&Wcat[(n * 16 + la) * 256 + k]);
            acc0[n] = __builtin_amdgcn_mfma_f32_16x16x32_bf16(a0, b, acc0[n], 0, 0, 0);
            acc1[n] = __builtin_amdgcn_mfma_f32_16x16x32_bf16(a1, b, acc1[n], 0, 0, 0);
        }
    }

    // D layout: col = lane&15, row = (lane>>4)*4 + j
    int orow = row0 + (lane >> 4) * 4;
#pragma unroll
    for (int n = 0; n < 8; ++n) {
        int col = n * 16 + la;
        float bv = bias[col];
#pragma unroll
        for (int j = 0; j < 4; ++j) {
            int r0 = orow + j;
            if (r0 < N) {
                float xv = acc0[n][j] + bv;
                float g = 0.5f * xv * (1.0f + erff(xv * 0.70710678118654752f));
                out[(size_t)r0 * 128 + col] = __float2bfloat16(g);
            }
            int r1 = orow + 16 + j;
            if (r1 < N) {
                float xv = acc1[n][j] + bv;
                float g = 0.5f * xv * (1.0f + erff(xv * 0.70710678118654752f));
                out[(size_t)r1 * 128 + col] = __float2bfloat16(g);
            }
        }
    }
}

// chunk-parallel partial pooling: block (1 wave) sums 64 contiguous nodes,
// atomicAdd per graph-segment into pooled[G][128] (fp32).
__global__ void pool_partial(const __hip_bfloat16* __restrict__ h,
                             const int* __restrict__ batch,
                             float* __restrict__ pooled, int N) {
    int i0 = blockIdx.x * 64;
    int i1 = min(i0 + 64, N);
    if (i0 >= N) return;
    int lane = threadIdx.x;  // 64
    const unsigned* hu = (const unsigned*)h;
    float ax = 0.f, ay = 0.f;
    int cur = batch[i0];
    for (int i = i0; i < i1; ++i) {
        int b = batch[i];
        if (b != cur) {
            atomicAdd(&pooled[cur * 128 + lane * 2], ax);
            atomicAdd(&pooled[cur * 128 + lane * 2 + 1], ay);
            ax = 0.f; ay = 0.f; cur = b;
        }
        unsigned v = hu[(size_t)i * 64 + lane];
        ax += bf16lo(v); ay += bf16hi(v);
    }
    atomicAdd(&pooled[cur * 128 + lane * 2], ax);
    atomicAdd(&pooled[cur * 128 + lane * 2 + 1], ay);
}

// finish: out[g] = (pooled[g]/count) . Wout + bout
__global__ void pool_finish(const float* __restrict__ pooled,
                            const int* __restrict__ gstart,
                            const float* __restrict__ Wout,
                            const float* __restrict__ bout,
                            float* __restrict__ out) {
    int g = blockIdx.x;
    int f = threadIdx.x;  // 128
    float cnt = (float)(gstart[g + 1] - gstart[g]);
    float v = pooled[g * 128 + f] * Wout[f];
    __shared__ float red[128];
    red[f] = v;
    __syncthreads();
    for (int off = 64; off > 0; off >>= 1) {
        if (f < off) red[f] += red[f + off];
        __syncthreads();
    }
    if (f == 0) out[g] = red[0] / fmaxf(cnt, 1.0f) + bout[0];
}

// ---------------- launch ----------------

extern "C" void kernel_launch(void* const* d_in, const int* in_sizes, int n_in,
                              void* d_out, int out_size, void* d_ws, size_t ws_size,
                              hipStream_t stream) {
    const float* x          = (const float*)d_in[0];
    const int*   edge_index = (const int*)d_in[1];
    const int*   batch      = (const int*)d_in[2];
    const float* Wroot[4] = {(const float*)d_in[3], (const float*)d_in[6],
                             (const float*)d_in[9], (const float*)d_in[12]};
    const float* Wrel[4]  = {(const float*)d_in[4], (const float*)d_in[7],
                             (const float*)d_in[10], (const float*)d_in[13]};
    const float* bias[4]  = {(const float*)d_in[5], (const float*)d_in[8],
                             (const float*)d_in[11], (const float*)d_in[14]};
    const float* Wout = (const float*)d_in[15];
    const float* bout = (const float*)d_in[16];
    float* out = (float*)d_out;

    const int N = in_sizes[2];       // 40000
    const int E = in_sizes[1] / 2;   // 640000
    const int G = 128;
    const int* src = edge_index;
    const int* dst = edge_index + E;

    char* ws = (char*)d_ws;
    size_t o = 0;
    auto alloc = [&](size_t bytes) { void* p = ws + o; o += (bytes + 255) & ~(size_t)255; return p; };

    __hip_bfloat16* hx   = (__hip_bfloat16*)alloc((size_t)N * 128 * 2);
    __hip_bfloat16* hb0  = (__hip_bfloat16*)alloc((size_t)N * 128 * 2);
    __hip_bfloat16* hb1  = (__hip_bfloat16*)alloc((size_t)N * 128 * 2);
    __hip_bfloat16* agg  = (__hip_bfloat16*)alloc((size_t)N * 128 * 2);
    __hip_bfloat16* wcat[4];
    for (int l = 0; l < 4; ++l) wcat[l] = (__hip_bfloat16*)alloc(128 * 256 * 2);
    int* deg     = (int*)alloc((size_t)N * 4);
    int* offsets = (int*)alloc((size_t)(N + 1) * 4);
    int* cursor  = (int*)alloc((size_t)N * 4);
    int* sorted  = (int*)alloc((size_t)E * 4);
    int* gstart  = (int*)alloc((size_t)(G + 1) * 4);
    float* pooled = (float*)alloc((size_t)G * 128 * 4);

    // CSR build (reused by all 4 layers)
    hipMemsetAsync(deg, 0, (size_t)N * 4, stream);
    degree_kernel<<<(E + 255) / 256, 256, 0, stream>>>(dst, deg, E);
    scan_kernel<<<1, 1024, 0, stream>>>(deg, offsets, cursor, N);
    scatter_kernel<<<(E + 255) / 256, 256, 0, stream>>>(src, dst, cursor, sorted, E);
    bounds_kernel<<<1, 256, 0, stream>>>(batch, gstart, N, G);

    // input & weight conversion to bf16
    cvt_f32_to_bf16<<<(N * 128 + 255) / 256, 256, 0, stream>>>(x, hx, N * 128);
    for (int l = 0; l < 4; ++l)
        build_wcat<<<(128 * 256 + 255) / 256, 256, 0, stream>>>(Wroot[l], Wrel[l], wcat[l]);

    // 4 GraphConv + gelu layers
    __hip_bfloat16* hin = hx;
    __hip_bfloat16* houts[4] = {hb0, hb1, hb0, hb1};
    for (int l = 0; l < 4; ++l) {
        agg_kernel<<<(N + 3) / 4, 256, 0, stream>>>(hin, offsets, sorted, agg, N);
        gemm_layer_kernel<<<(N + 127) / 128, 256, 0, stream>>>(hin, agg, wcat[l], bias[l], houts[l], N);
        hin = houts[l];
    }

    // mean pool + output head
    hipMemsetAsync(pooled, 0, (size_t)G * 128 * 4, stream);
    pool_partial<<<(N + 63) / 64, 64, 0, stream>>>(hin, batch, pooled, N);
    pool_finish<<<G, 128, 0, stream>>>(pooled, gstart, Wout, bout, out);
}

// Round 5
// 458.224 us; speedup vs baseline: 1.8756x; 1.0762x over previous
//
#include <hip/hip_runtime.h>
#include <hip/hip_bf16.h>

typedef __bf16 bf16x8 __attribute__((ext_vector_type(8)));
typedef float  f32x4  __attribute__((ext_vector_type(4)));

__device__ __forceinline__ float bf16lo(unsigned v) { return __uint_as_float(v << 16); }
__device__ __forceinline__ float bf16hi(unsigned v) { return __uint_as_float(v & 0xffff0000u); }

// tanh-form gelu via fast exp; |err| ~3e-4, invisible vs bf16 storage rounding.
// exp overflow/underflow saturate correctly (inf -> tanh=1, 0 -> tanh=-1).
__device__ __forceinline__ float gelu_f(float x) {
    float t = 0.7978845608028654f * (x + 0.044715f * x * x * x);
    float e = __expf(2.0f * t);
    float th = 1.0f - 2.0f / (1.0f + e);
    return 0.5f * x * (1.0f + th);
}

// ---------------- preprocessing kernels ----------------

__global__ void degree_kernel(const int* __restrict__ dst, int* __restrict__ deg, int E) {
    int e = blockIdx.x * blockDim.x + threadIdx.x;
    if (e < E) atomicAdd(&deg[dst[e]], 1);
}

__global__ void scan_kernel(const int* __restrict__ deg, int* __restrict__ offsets,
                            int* __restrict__ cursor, int n) {
    __shared__ int wsum[16];
    __shared__ int carry_s;
    if (threadIdx.x == 0) carry_s = 0;
    __syncthreads();
    int lane = threadIdx.x & 63;
    int wave = threadIdx.x >> 6;
    for (int base = 0; base < n; base += 1024) {
        int i = base + threadIdx.x;
        int v = (i < n) ? deg[i] : 0;
        int s = v;
#pragma unroll
        for (int off = 1; off < 64; off <<= 1) {
            int t = __shfl_up(s, off, 64);
            if (lane >= off) s += t;
        }
        if (lane == 63) wsum[wave] = s;
        __syncthreads();
        if (wave == 0 && lane < 16) {
            int ws = wsum[lane];
            int ss = ws;
#pragma unroll
            for (int off = 1; off < 16; off <<= 1) {
                int t = __shfl_up(ss, off, 64);
                if (lane >= off) ss += t;
            }
            wsum[lane] = ss - ws;
        }
        __syncthreads();
        int excl = (s - v) + wsum[wave];
        int carry = carry_s;
        if (i < n) { offsets[i] = carry + excl; cursor[i] = carry + excl; }
        __syncthreads();
        if (threadIdx.x == 1023) carry_s = carry + excl + v;
        __syncthreads();
    }
    if (threadIdx.x == 0) offsets[n] = carry_s;
}

__global__ void scatter_kernel(const int* __restrict__ src, const int* __restrict__ dst,
                               int* __restrict__ cursor, int* __restrict__ sorted_src, int E) {
    int e = blockIdx.x * blockDim.x + threadIdx.x;
    if (e < E) {
        int d = dst[e];
        int pos = atomicAdd(&cursor[d], 1);
        sorted_src[pos] = src[e];
    }
}

__global__ void bounds_kernel(const int* __restrict__ batch, int* __restrict__ gstart,
                              int N, int G) {
    int g = blockIdx.x * blockDim.x + threadIdx.x;
    if (g <= G) {
        int lo = 0, hi = N;
        while (lo < hi) {
            int mid = (lo + hi) >> 1;
            if (batch[mid] < g) lo = mid + 1; else hi = mid;
        }
        gstart[g] = lo;
    }
}

__global__ void cvt_f32_to_bf16(const float* __restrict__ in,
                                __hip_bfloat16* __restrict__ out, int n) {
    int i = blockIdx.x * blockDim.x + threadIdx.x;
    if (i < n) out[i] = __float2bfloat16(in[i]);
}

__global__ void build_wcat(const float* __restrict__ Wr, const float* __restrict__ Wn,
                           __hip_bfloat16* __restrict__ Wcat) {
    int idx = blockIdx.x * blockDim.x + threadIdx.x;
    if (idx < 128 * 256) {
        int j = idx >> 8, k = idx & 255;
        float v = (k < 128) ? Wr[j * 128 + k] : Wn[j * 128 + (k - 128)];
        Wcat[idx] = __float2bfloat16(v);
    }
}

// ---------------- per-layer kernels ----------------

// 1 wave per node; lane owns features [2*lane, 2*lane+1]. ILP ladder 8/4/2/1.
__global__ void agg_kernel(const __hip_bfloat16* __restrict__ h,
                           const int* __restrict__ offsets,
                           const int* __restrict__ sorted_src,
                           __hip_bfloat16* __restrict__ agg, int N) {
    int node = blockIdx.x * (blockDim.x >> 6) + (threadIdx.x >> 6);
    int lane = threadIdx.x & 63;
    if (node >= N) return;
    int s = offsets[node], e = offsets[node + 1];
    const unsigned* hu = (const unsigned*)h;
    float a0x = 0.f, a0y = 0.f, a1x = 0.f, a1y = 0.f;
    float a2x = 0.f, a2y = 0.f, a3x = 0.f, a3y = 0.f;
    int t = s;
    for (; t + 8 <= e; t += 8) {
        int n0 = sorted_src[t],     n1 = sorted_src[t + 1];
        int n2 = sorted_src[t + 2], n3 = sorted_src[t + 3];
        int n4 = sorted_src[t + 4], n5 = sorted_src[t + 5];
        int n6 = sorted_src[t + 6], n7 = sorted_src[t + 7];
        unsigned v0 = hu[(size_t)n0 * 64 + lane];
        unsigned v1 = hu[(size_t)n1 * 64 + lane];
        unsigned v2 = hu[(size_t)n2 * 64 + lane];
        unsigned v3 = hu[(size_t)n3 * 64 + lane];
        unsigned v4 = hu[(size_t)n4 * 64 + lane];
        unsigned v5 = hu[(size_t)n5 * 64 + lane];
        unsigned v6 = hu[(size_t)n6 * 64 + lane];
        unsigned v7 = hu[(size_t)n7 * 64 + lane];
        a0x += bf16lo(v0); a0y += bf16hi(v0);
        a1x += bf16lo(v1); a1y += bf16hi(v1);
        a2x += bf16lo(v2); a2y += bf16hi(v2);
        a3x += bf16lo(v3); a3y += bf16hi(v3);
        a0x += bf16lo(v4); a0y += bf16hi(v4);
        a1x += bf16lo(v5); a1y += bf16hi(v5);
        a2x += bf16lo(v6); a2y += bf16hi(v6);
        a3x += bf16lo(v7); a3y += bf16hi(v7);
    }
    if (t + 4 <= e) {
        int n0 = sorted_src[t],     n1 = sorted_src[t + 1];
        int n2 = sorted_src[t + 2], n3 = sorted_src[t + 3];
        unsigned v0 = hu[(size_t)n0 * 64 + lane];
        unsigned v1 = hu[(size_t)n1 * 64 + lane];
        unsigned v2 = hu[(size_t)n2 * 64 + lane];
        unsigned v3 = hu[(size_t)n3 * 64 + lane];
        a0x += bf16lo(v0); a0y += bf16hi(v0);
        a1x += bf16lo(v1); a1y += bf16hi(v1);
        a2x += bf16lo(v2); a2y += bf16hi(v2);
        a3x += bf16lo(v3); a3y += bf16hi(v3);
        t += 4;
    }
    if (t + 2 <= e) {
        int n0 = sorted_src[t], n1 = sorted_src[t + 1];
        unsigned v0 = hu[(size_t)n0 * 64 + lane];
        unsigned v1 = hu[(size_t)n1 * 64 + lane];
        a0x += bf16lo(v0); a0y += bf16hi(v0);
        a1x += bf16lo(v1); a1y += bf16hi(v1);
        t += 2;
    }
    if (t < e) {
        unsigned v = hu[(size_t)sorted_src[t] * 64 + lane];
        a0x += bf16lo(v); a0y += bf16hi(v);
    }
    float sx = (a0x + a1x) + (a2x + a3x);
    float sy = (a0y + a1y) + (a2y + a3y);
    __hip_bfloat162 o;
    o.x = __float2bfloat16(sx);
    o.y = __float2bfloat16(sy);
    *reinterpret_cast<__hip_bfloat162*>(&agg[(size_t)node * 128 + lane * 2]) = o;
}

// out = gelu( [h | agg] @ Wcat^T + b )
// Wave tile: 128 rows x 16 cols. B-frags (8 x bf16x8) in registers, loaded ONCE,
// reused across 8 row-tiles. 2500 waves total (vs 1252 before) for latency hiding.
// Block: 4 waves = 4 colgroups over the same 128 rows (A addresses shared -> L1 hits).
__global__ void gemm_layer_kernel(const __hip_bfloat16* __restrict__ h,
                                  const __hip_bfloat16* __restrict__ agg,
                                  const __hip_bfloat16* __restrict__ Wcat,  // [128][256]
                                  const float* __restrict__ bias,           // [128]
                                  __hip_bfloat16* __restrict__ out, int N) {
    int wave = threadIdx.x >> 6;
    int lane = threadIdx.x & 63;
    int row0 = (blockIdx.x >> 1) * 128;
    int cg   = ((blockIdx.x & 1) << 2) | wave;   // colgroup 0..7
    if (row0 >= N) return;

    int la  = lane & 15;          // B-col / A-row within 16-tile
    int ke0 = (lane >> 4) * 8;    // k element offset within 32-chunk
    int col = cg * 16 + la;

    // B fragments once (16KB per wave -> 32 VGPR)
    bf16x8 b[8];
#pragma unroll
    for (int ks = 0; ks < 8; ++ks)
        b[ks] = *reinterpret_cast<const bf16x8*>(&Wcat[(size_t)col * 256 + ks * 32 + ke0]);

    float bv = bias[col];

    f32x4 acc[8];
#pragma unroll
    for (int m = 0; m < 8; ++m) {
        int r = row0 + m * 16 + la;
        if (r >= N) r = N - 1;
        const __hip_bfloat16* hr = &h[(size_t)r * 128];
        const __hip_bfloat16* ar = &agg[(size_t)r * 128];
        bf16x8 a[8];
#pragma unroll
        for (int ks = 0; ks < 4; ++ks) {
            a[ks]     = *reinterpret_cast<const bf16x8*>(&hr[ks * 32 + ke0]);
            a[ks + 4] = *reinterpret_cast<const bf16x8*>(&ar[ks * 32 + ke0]);
        }
        f32x4 c = {};
#pragma unroll
        for (int ks = 0; ks < 8; ++ks)
            c = __builtin_amdgcn_mfma_f32_16x16x32_bf16(a[ks], b[ks], c, 0, 0, 0);
        acc[m] = c;
    }

    // D layout: col = lane&15, row = (lane>>4)*4 + j
    int r0 = row0 + (lane >> 4) * 4;
#pragma unroll
    for (int m = 0; m < 8; ++m) {
#pragma unroll
        for (int j = 0; j < 4; ++j) {
            int r = r0 + m * 16 + j;
            if (r < N) {
                float xv = acc[m][j] + bv;
                out[(size_t)r * 128 + col] = __float2bfloat16(gelu_f(xv));
            }
        }
    }
}

// chunk-parallel partial pooling
__global__ void pool_partial(const __hip_bfloat16* __restrict__ h,
                             const int* __restrict__ batch,
                             float* __restrict__ pooled, int N) {
    int i0 = blockIdx.x * 64;
    int i1 = min(i0 + 64, N);
    if (i0 >= N) return;
    int lane = threadIdx.x;  // 64
    const unsigned* hu = (const unsigned*)h;
    float ax = 0.f, ay = 0.f;
    int cur = batch[i0];
    for (int i = i0; i < i1; ++i) {
        int b = batch[i];
        if (b != cur) {
            atomicAdd(&pooled[cur * 128 + lane * 2], ax);
            atomicAdd(&pooled[cur * 128 + lane * 2 + 1], ay);
            ax = 0.f; ay = 0.f; cur = b;
        }
        unsigned v = hu[(size_t)i * 64 + lane];
        ax += bf16lo(v); ay += bf16hi(v);
    }
    atomicAdd(&pooled[cur * 128 + lane * 2], ax);
    atomicAdd(&pooled[cur * 128 + lane * 2 + 1], ay);
}

__global__ void pool_finish(const float* __restrict__ pooled,
                            const int* __restrict__ gstart,
                            const float* __restrict__ Wout,
                            const float* __restrict__ bout,
                            float* __restrict__ out) {
    int g = blockIdx.x;
    int f = threadIdx.x;  // 128
    float cnt = (float)(gstart[g + 1] - gstart[g]);
    float v = pooled[g * 128 + f] * Wout[f];
    __shared__ float red[128];
    red[f] = v;
    __syncthreads();
    for (int off = 64; off > 0; off >>= 1) {
        if (f < off) red[f] += red[f + off];
        __syncthreads();
    }
    if (f == 0) out[g] = red[0] / fmaxf(cnt, 1.0f) + bout[0];
}

// ---------------- launch ----------------

extern "C" void kernel_launch(void* const* d_in, const int* in_sizes, int n_in,
                              void* d_out, int out_size, void* d_ws, size_t ws_size,
                              hipStream_t stream) {
    const float* x          = (const float*)d_in[0];
    const int*   edge_index = (const int*)d_in[1];
    const int*   batch      = (const int*)d_in[2];
    const float* Wroot[4] = {(const float*)d_in[3], (const float*)d_in[6],
                             (const float*)d_in[9], (const float*)d_in[12]};
    const float* Wrel[4]  = {(const float*)d_in[4], (const float*)d_in[7],
                             (const float*)d_in[10], (const float*)d_in[13]};
    const float* bias[4]  = {(const float*)d_in[5], (const float*)d_in[8],
                             (const float*)d_in[11], (const float*)d_in[14]};
    const float* Wout = (const float*)d_in[15];
    const float* bout = (const float*)d_in[16];
    float* out = (float*)d_out;

    const int N = in_sizes[2];       // 40000
    const int E = in_sizes[1] / 2;   // 640000
    const int G = 128;
    const int* src = edge_index;
    const int* dst = edge_index + E;

    char* ws = (char*)d_ws;
    size_t o = 0;
    auto alloc = [&](size_t bytes) { void* p = ws + o; o += (bytes + 255) & ~(size_t)255; return p; };

    __hip_bfloat16* hx   = (__hip_bfloat16*)alloc((size_t)N * 128 * 2);
    __hip_bfloat16* hb0  = (__hip_bfloat16*)alloc((size_t)N * 128 * 2);
    __hip_bfloat16* hb1  = (__hip_bfloat16*)alloc((size_t)N * 128 * 2);
    __hip_bfloat16* agg  = (__hip_bfloat16*)alloc((size_t)N * 128 * 2);
    __hip_bfloat16* wcat[4];
    for (int l = 0; l < 4; ++l) wcat[l] = (__hip_bfloat16*)alloc(128 * 256 * 2);
    int* deg     = (int*)alloc((size_t)N * 4);
    int* offsets = (int*)alloc((size_t)(N + 1) * 4);
    int* cursor  = (int*)alloc((size_t)N * 4);
    int* sorted  = (int*)alloc((size_t)E * 4);
    int* gstart  = (int*)alloc((size_t)(G + 1) * 4);
    float* pooled = (float*)alloc((size_t)G * 128 * 4);

    // CSR build (reused by all 4 layers)
    hipMemsetAsync(deg, 0, (size_t)N * 4, stream);
    degree_kernel<<<(E + 255) / 256, 256, 0, stream>>>(dst, deg, E);
    scan_kernel<<<1, 1024, 0, stream>>>(deg, offsets, cursor, N);
    scatter_kernel<<<(E + 255) / 256, 256, 0, stream>>>(src, dst, cursor, sorted, E);
    bounds_kernel<<<1, 256, 0, stream>>>(batch, gstart, N, G);

    // input & weight conversion to bf16
    cvt_f32_to_bf16<<<(N * 128 + 255) / 256, 256, 0, stream>>>(x, hx, N * 128);
    for (int l = 0; l < 4; ++l)
        build_wcat<<<(128 * 256 + 255) / 256, 256, 0, stream>>>(Wroot[l], Wrel[l], wcat[l]);

    // 4 GraphConv + gelu layers
    __hip_bfloat16* hin = hx;
    __hip_bfloat16* houts[4] = {hb0, hb1, hb0, hb1};
    for (int l = 0; l < 4; ++l) {
        agg_kernel<<<(N + 3) / 4, 256, 0, stream>>>(hin, offsets, sorted, agg, N);
        gemm_layer_kernel<<<((N + 127) / 128) * 2, 256, 0, stream>>>(hin, agg, wcat[l], bias[l], houts[l], N);
        hin = houts[l];
    }

    // mean pool + output head
    hipMemsetAsync(pooled, 0, (size_t)G * 128 * 4, stream);
    pool_partial<<<(N + 63) / 64, 64, 0, stream>>>(hin, batch, pooled, N);
    pool_finish<<<G, 128, 0, stream>>>(pooled, gstart, Wout, bout, out);
}

// Round 6
// 427.012 us; speedup vs baseline: 2.0127x; 1.0731x over previous
//
#include <hip/hip_runtime.h>
#include <hip/hip_bf16.h>

typedef __bf16 bf16x8 __attribute__((ext_vector_type(8)));
typedef float  f32x4  __attribute__((ext_vector_type(4)));

__device__ __forceinline__ float blo(unsigned v) { return __uint_as_float(v << 16); }
__device__ __forceinline__ float bhi(unsigned v) { return __uint_as_float(v & 0xffff0000u); }
// round-to-nearest-even f32 -> bf16 (finite inputs)
__device__ __forceinline__ unsigned short f2bf(float f) {
    unsigned u = __float_as_uint(f);
    u += 0x7fffu + ((u >> 16) & 1u);
    return (unsigned short)(u >> 16);
}
// tanh-form gelu via fast exp; |err| ~3e-4 (invisible vs bf16 storage rounding)
__device__ __forceinline__ float gelu_f(float x) {
    float t = 0.7978845608028654f * (x + 0.044715f * x * x * x);
    float e = __expf(2.0f * t);
    float th = 1.0f - 2.0f / (1.0f + e);
    return 0.5f * x * (1.0f + th);
}

// ---------------- preprocessing ----------------

__global__ void degree_kernel(const int* __restrict__ dst, int* __restrict__ deg, int E) {
    int e = blockIdx.x * blockDim.x + threadIdx.x;
    if (e < E) atomicAdd(&deg[dst[e]], 1);
}

// hierarchical scan: per-1024-chunk sums
__global__ void chunk_sum_kernel(const int* __restrict__ deg, int* __restrict__ bsum, int n) {
    int i = blockIdx.x * 1024 + threadIdx.x;
    int v = (i < n) ? deg[i] : 0;
#pragma unroll
    for (int m = 1; m < 64; m <<= 1) v += __shfl_xor(v, m, 64);
    __shared__ int ws[16];
    int wave = threadIdx.x >> 6, lane = threadIdx.x & 63;
    if (lane == 0) ws[wave] = v;
    __syncthreads();
    if (threadIdx.x == 0) {
        int s = 0;
#pragma unroll
        for (int k = 0; k < 16; ++k) s += ws[k];
        bsum[blockIdx.x] = s;
    }
}

// 1 wave: exclusive scan of nb (<=64) chunk sums; also writes offsets[n]=E
__global__ void chunk_scan_kernel(const int* __restrict__ bsum, int* __restrict__ bbase,
                                  int nb, int* __restrict__ offsets, int n, int E) {
    int lane = threadIdx.x;  // 64
    int v = (lane < nb) ? bsum[lane] : 0;
    int s = v;
#pragma unroll
    for (int m = 1; m < 64; m <<= 1) {
        int t = __shfl_up(s, m, 64);
        if (lane >= m) s += t;
    }
    if (lane < nb) bbase[lane] = s - v;
    if (lane == 0) offsets[n] = E;
}

__global__ void scan_apply_kernel(const int* __restrict__ deg, const int* __restrict__ bbase,
                                  int* __restrict__ offsets, int* __restrict__ cursor, int n) {
    int i = blockIdx.x * 1024 + threadIdx.x;
    int lane = threadIdx.x & 63, wave = threadIdx.x >> 6;
    int v = (i < n) ? deg[i] : 0;
    int s = v;
#pragma unroll
    for (int m = 1; m < 64; m <<= 1) {
        int t = __shfl_up(s, m, 64);
        if (lane >= m) s += t;
    }
    __shared__ int ws[16];
    if (lane == 63) ws[wave] = s;
    __syncthreads();
    if (wave == 0 && lane < 16) {
        int wv = ws[lane];
        int ss = wv;
#pragma unroll
        for (int m = 1; m < 16; m <<= 1) {
            int t = __shfl_up(ss, m, 64);
            if (lane >= m) ss += t;
        }
        ws[lane] = ss - wv;
    }
    __syncthreads();
    int excl = (s - v) + ws[wave] + bbase[blockIdx.x];
    if (i < n) { offsets[i] = excl; cursor[i] = excl; }
}

__global__ void scatter_kernel(const int* __restrict__ src, const int* __restrict__ dst,
                               int* __restrict__ cursor, int* __restrict__ sorted_src, int E) {
    int e = blockIdx.x * blockDim.x + threadIdx.x;
    if (e < E) {
        int d = dst[e];
        int pos = atomicAdd(&cursor[d], 1);
        sorted_src[pos] = src[e];
    }
}

__global__ void bounds_kernel(const int* __restrict__ batch, int* __restrict__ gstart,
                              int N, int G) {
    int g = blockIdx.x * blockDim.x + threadIdx.x;
    if (g <= G) {
        int lo = 0, hi = N;
        while (lo < hi) {
            int mid = (lo + hi) >> 1;
            if (batch[mid] < g) lo = mid + 1; else hi = mid;
        }
        gstart[g] = lo;
    }
}

__global__ void cvt_kernel(const float4* __restrict__ in, ushort4* __restrict__ out, int n4) {
    int i = blockIdx.x * blockDim.x + threadIdx.x;
    if (i < n4) {
        float4 f = in[i];
        ushort4 o; o.x = f2bf(f.x); o.y = f2bf(f.y); o.z = f2bf(f.z); o.w = f2bf(f.w);
        out[i] = o;
    }
}

__global__ void build_wcat(const float* __restrict__ Wr, const float* __restrict__ Wn,
                           __hip_bfloat16* __restrict__ Wcat) {
    int idx = blockIdx.x * blockDim.x + threadIdx.x;
    if (idx < 128 * 256) {
        int j = idx >> 8, k = idx & 255;
        float v = (k < 128) ? Wr[j * 128 + k] : Wn[j * 128 + (k - 128)];
        Wcat[idx] = __float2bfloat16(v);
    }
}

// ---------------- per-layer kernels ----------------

// 1 wave/node; lane owns 8B (4 feats); one load covers 2 neighbor rows (lane>>5
// selects which). Unroll x4 -> 8 neighbors in flight. Cross-half shfl merge.
__global__ void agg_kernel(const __hip_bfloat16* __restrict__ h,
                           const int* __restrict__ offsets,
                           const int* __restrict__ sorted_src,
                           __hip_bfloat16* __restrict__ agg, int N) {
    int node = blockIdx.x * 4 + (threadIdx.x >> 6);
    int lane = threadIdx.x & 63;
    if (node >= N) return;
    int s = offsets[node], e = offsets[node + 1];
    int half = lane >> 5, fl = lane & 31;
    const uint2* hu = (const uint2*)h;
    f32x4 A0 = {0,0,0,0}, A1 = {0,0,0,0}, A2 = {0,0,0,0}, A3 = {0,0,0,0};
    int t = s;
    for (; t + 8 <= e; t += 8) {
        int j0 = sorted_src[t + half];
        int j1 = sorted_src[t + 2 + half];
        int j2 = sorted_src[t + 4 + half];
        int j3 = sorted_src[t + 6 + half];
        uint2 v0 = hu[(size_t)j0 * 32 + fl];
        uint2 v1 = hu[(size_t)j1 * 32 + fl];
        uint2 v2 = hu[(size_t)j2 * 32 + fl];
        uint2 v3 = hu[(size_t)j3 * 32 + fl];
        A0[0] += blo(v0.x); A0[1] += bhi(v0.x); A0[2] += blo(v0.y); A0[3] += bhi(v0.y);
        A1[0] += blo(v1.x); A1[1] += bhi(v1.x); A1[2] += blo(v1.y); A1[3] += bhi(v1.y);
        A2[0] += blo(v2.x); A2[1] += bhi(v2.x); A2[2] += blo(v2.y); A2[3] += bhi(v2.y);
        A3[0] += blo(v3.x); A3[1] += bhi(v3.x); A3[2] += blo(v3.y); A3[3] += bhi(v3.y);
    }
    if (t + 4 <= e) {
        int j0 = sorted_src[t + half];
        int j1 = sorted_src[t + 2 + half];
        uint2 v0 = hu[(size_t)j0 * 32 + fl];
        uint2 v1 = hu[(size_t)j1 * 32 + fl];
        A0[0] += blo(v0.x); A0[1] += bhi(v0.x); A0[2] += blo(v0.y); A0[3] += bhi(v0.y);
        A1[0] += blo(v1.x); A1[1] += bhi(v1.x); A1[2] += blo(v1.y); A1[3] += bhi(v1.y);
        t += 4;
    }
    if (t + 2 <= e) {
        int j0 = sorted_src[t + half];
        uint2 v0 = hu[(size_t)j0 * 32 + fl];
        A0[0] += blo(v0.x); A0[1] += bhi(v0.x); A0[2] += blo(v0.y); A0[3] += bhi(v0.y);
        t += 2;
    }
    if (t < e && half == 0) {   // odd tail: only lo-half loads the last row
        int j = sorted_src[t];
        uint2 v = hu[(size_t)j * 32 + fl];
        A1[0] += blo(v.x); A1[1] += bhi(v.x); A1[2] += blo(v.y); A1[3] += bhi(v.y);
    }
    f32x4 A;
#pragma unroll
    for (int q = 0; q < 4; ++q) {
        float a = (A0[q] + A1[q]) + (A2[q] + A3[q]);
        a += __shfl_xor(a, 32, 64);
        A[q] = a;
    }
    if (half == 0) {
        ushort4 o; o.x = f2bf(A[0]); o.y = f2bf(A[1]); o.z = f2bf(A[2]); o.w = f2bf(A[3]);
        *reinterpret_cast<ushort4*>(&agg[(size_t)node * 128 + fl * 4]) = o;
    }
}

// out = gelu([h | agg] @ Wcat^T + b). Wave tile 64 rows x 16 cols; B-frags in
// registers (loaded once); block = 8 waves = all 8 colgroups over same 64 rows
// (A shared via L1). 5000 waves total for latency hiding.
__global__ __launch_bounds__(512, 4)
void gemm_layer_kernel(const __hip_bfloat16* __restrict__ h,
                       const __hip_bfloat16* __restrict__ agg,
                       const __hip_bfloat16* __restrict__ Wcat,  // [128][256]
                       const float* __restrict__ bias,           // [128]
                       __hip_bfloat16* __restrict__ out, int N) {
    int wave = threadIdx.x >> 6;     // colgroup 0..7
    int lane = threadIdx.x & 63;
    int row0 = blockIdx.x * 64;
    int la  = lane & 15;
    int ke0 = (lane >> 4) * 8;
    int col = wave * 16 + la;

    bf16x8 b[8];
#pragma unroll
    for (int ks = 0; ks < 8; ++ks)
        b[ks] = *reinterpret_cast<const bf16x8*>(&Wcat[(size_t)col * 256 + ks * 32 + ke0]);
    float bv = bias[col];

    f32x4 acc[4];
#pragma unroll
    for (int m = 0; m < 4; ++m) {
        int r = row0 + m * 16 + la;
        if (r >= N) r = N - 1;
        const __hip_bfloat16* hr = &h[(size_t)r * 128];
        const __hip_bfloat16* ar = &agg[(size_t)r * 128];
        bf16x8 a[8];
#pragma unroll
        for (int ks = 0; ks < 4; ++ks) {
            a[ks]     = *reinterpret_cast<const bf16x8*>(&hr[ks * 32 + ke0]);
            a[ks + 4] = *reinterpret_cast<const bf16x8*>(&ar[ks * 32 + ke0]);
        }
        f32x4 c = {0, 0, 0, 0};
#pragma unroll
        for (int ks = 0; ks < 8; ++ks)
            c = __builtin_amdgcn_mfma_f32_16x16x32_bf16(a[ks], b[ks], c, 0, 0, 0);
        acc[m] = c;
    }

    int r0 = row0 + (lane >> 4) * 4;
#pragma unroll
    for (int m = 0; m < 4; ++m) {
#pragma unroll
        for (int j = 0; j < 4; ++j) {
            int r = r0 + m * 16 + j;
            if (r < N)
                out[(size_t)r * 128 + col] = __float2bfloat16(gelu_f(acc[m][j] + bv));
        }
    }
}

// pooling fused with Wout-dot: wave handles 16 nodes (8 paired 8B loads in
// flight); per-lane dot vs Wout; per-half shuffle reduce -> 1 atomic per
// graph-segment per half into outsum[G].
__global__ void pool_partial(const __hip_bfloat16* __restrict__ h,
                             const int* __restrict__ batch,
                             const float* __restrict__ Wout,
                             float* __restrict__ outsum, int N) {
    int wid = blockIdx.x * 4 + (threadIdx.x >> 6);
    int lane = threadIdx.x & 63;
    int i0 = wid * 16;
    if (i0 >= N) return;
    int half = lane >> 5, fl = lane & 31;
    const uint2* hu = (const uint2*)h;
    float w0 = Wout[4 * fl], w1 = Wout[4 * fl + 1];
    float w2 = Wout[4 * fl + 2], w3 = Wout[4 * fl + 3];
    float dot = 0.f;
    int cur = -1;
#pragma unroll
    for (int t = 0; t < 8; ++t) {
        int i = i0 + 2 * t + half;
        if (i < N) {
            int g = batch[i];
            uint2 v = hu[(size_t)i * 32 + fl];
            float d = blo(v.x) * w0 + bhi(v.x) * w1 + blo(v.y) * w2 + bhi(v.y) * w3;
            if (g != cur) {     // uniform within a half (same i for all 32 lanes)
                if (cur >= 0) {
                    float r = dot;
#pragma unroll
                    for (int m = 16; m >= 1; m >>= 1) r += __shfl_xor(r, m, 64);
                    if (fl == 0) atomicAdd(&outsum[cur], r);
                }
                cur = g; dot = d;
            } else {
                dot += d;
            }
        }
    }
    if (cur >= 0) {
        float r = dot;
#pragma unroll
        for (int m = 16; m >= 1; m >>= 1) r += __shfl_xor(r, m, 64);
        if (fl == 0) atomicAdd(&outsum[cur], r);
    }
}

__global__ void pool_finish(const float* __restrict__ outsum,
                            const int* __restrict__ gstart,
                            const float* __restrict__ bout,
                            float* __restrict__ out, int G) {
    int g = blockIdx.x * blockDim.x + threadIdx.x;
    if (g < G) {
        float cnt = (float)(gstart[g + 1] - gstart[g]);
        out[g] = outsum[g] / fmaxf(cnt, 1.0f) + bout[0];
    }
}

// ---------------- launch ----------------

extern "C" void kernel_launch(void* const* d_in, const int* in_sizes, int n_in,
                              void* d_out, int out_size, void* d_ws, size_t ws_size,
                              hipStream_t stream) {
    const float* x          = (const float*)d_in[0];
    const int*   edge_index = (const int*)d_in[1];
    const int*   batch      = (const int*)d_in[2];
    const float* Wroot[4] = {(const float*)d_in[3], (const float*)d_in[6],
                             (const float*)d_in[9], (const float*)d_in[12]};
    const float* Wrel[4]  = {(const float*)d_in[4], (const float*)d_in[7],
                             (const float*)d_in[10], (const float*)d_in[13]};
    const float* bias[4]  = {(const float*)d_in[5], (const float*)d_in[8],
                             (const float*)d_in[11], (const float*)d_in[14]};
    const float* Wout = (const float*)d_in[15];
    const float* bout = (const float*)d_in[16];
    float* out = (float*)d_out;

    const int N = in_sizes[2];       // 40000
    const int E = in_sizes[1] / 2;   // 640000
    const int G = 128;
    const int* src = edge_index;
    const int* dst = edge_index + E;

    char* ws = (char*)d_ws;
    size_t o = 0;
    auto alloc = [&](size_t bytes) { void* p = ws + o; o += (bytes + 255) & ~(size_t)255; return p; };

    __hip_bfloat16* hx   = (__hip_bfloat16*)alloc((size_t)N * 128 * 2);
    __hip_bfloat16* hb0  = (__hip_bfloat16*)alloc((size_t)N * 128 * 2);
    __hip_bfloat16* hb1  = (__hip_bfloat16*)alloc((size_t)N * 128 * 2);
    __hip_bfloat16* agg  = (__hip_bfloat16*)alloc((size_t)N * 128 * 2);
    __hip_bfloat16* wcat[4];
    for (int l = 0; l < 4; ++l) wcat[l] = (__hip_bfloat16*)alloc(128 * 256 * 2);
    int* deg     = (int*)alloc((size_t)N * 4);
    int* offsets = (int*)alloc((size_t)(N + 1) * 4);
    int* cursor  = (int*)alloc((size_t)N * 4);
    int* sorted  = (int*)alloc((size_t)E * 4);
    int* gstart  = (int*)alloc((size_t)(G + 1) * 4);
    int* bsum    = (int*)alloc(64 * 4);
    int* bbase   = (int*)alloc(64 * 4);
    float* outsum = (float*)alloc((size_t)G * 4);

    const int nb = (N + 1023) / 1024;   // 40 (<=64 required by chunk_scan)

    // CSR build (reused by all 4 layers)
    hipMemsetAsync(deg, 0, (size_t)N * 4, stream);
    degree_kernel<<<(E + 255) / 256, 256, 0, stream>>>(dst, deg, E);
    chunk_sum_kernel<<<nb, 1024, 0, stream>>>(deg, bsum, N);
    chunk_scan_kernel<<<1, 64, 0, stream>>>(bsum, bbase, nb, offsets, N, E);
    scan_apply_kernel<<<nb, 1024, 0, stream>>>(deg, bbase, offsets, cursor, N);
    scatter_kernel<<<(E + 255) / 256, 256, 0, stream>>>(src, dst, cursor, sorted, E);
    bounds_kernel<<<1, 256, 0, stream>>>(batch, gstart, N, G);

    // input & weight conversion to bf16
    cvt_kernel<<<(N * 128 / 4 + 255) / 256, 256, 0, stream>>>(
        (const float4*)x, (ushort4*)hx, N * 128 / 4);
    for (int l = 0; l < 4; ++l)
        build_wcat<<<(128 * 256 + 255) / 256, 256, 0, stream>>>(Wroot[l], Wrel[l], wcat[l]);

    // 4 GraphConv + gelu layers
    __hip_bfloat16* hin = hx;
    __hip_bfloat16* houts[4] = {hb0, hb1, hb0, hb1};
    for (int l = 0; l < 4; ++l) {
        agg_kernel<<<(N + 3) / 4, 256, 0, stream>>>(hin, offsets, sorted, agg, N);
        gemm_layer_kernel<<<(N + 63) / 64, 512, 0, stream>>>(hin, agg, wcat[l], bias[l], houts[l], N);
        hin = houts[l];
    }

    // fused mean pool + output head
    hipMemsetAsync(outsum, 0, (size_t)G * 4, stream);
    pool_partial<<<((N + 15) / 16 + 3) / 4, 256, 0, stream>>>(hin, batch, Wout, outsum, N);
    pool_finish<<<1, 128, 0, stream>>>(outsum, gstart, bout, out, G);
}

// Round 9
// 399.369 us; speedup vs baseline: 2.1520x; 1.0692x over previous
//
#include <hip/hip_runtime.h>
#include <hip/hip_bf16.h>

typedef __bf16 bf16x8 __attribute__((ext_vector_type(8)));
typedef float  f32x4  __attribute__((ext_vector_type(4)));

__device__ __forceinline__ float blo(unsigned v) { return __uint_as_float(v << 16); }
__device__ __forceinline__ float bhi(unsigned v) { return __uint_as_float(v & 0xffff0000u); }
// round-to-nearest-even f32 -> bf16 (finite inputs)
__device__ __forceinline__ unsigned short f2bf(float f) {
    unsigned u = __float_as_uint(f);
    u += 0x7fffu + ((u >> 16) & 1u);
    return (unsigned short)(u >> 16);
}
// tanh-form gelu via fast exp; |err| ~3e-4 (invisible vs bf16 storage rounding)
__device__ __forceinline__ float gelu_f(float x) {
    float t = 0.7978845608028654f * (x + 0.044715f * x * x * x);
    float e = __expf(2.0f * t);
    float th = 1.0f - 2.0f / (1.0f + e);
    return 0.5f * x * (1.0f + th);
}

// ---------------- preprocessing ----------------

__global__ void degree_kernel(const int* __restrict__ dst, int* __restrict__ deg, int E) {
    int e = blockIdx.x * blockDim.x + threadIdx.x;
    if (e < E) atomicAdd(&deg[dst[e]], 1);
}

__global__ void chunk_sum_kernel(const int* __restrict__ deg, int* __restrict__ bsum, int n) {
    int i = blockIdx.x * 1024 + threadIdx.x;
    int v = (i < n) ? deg[i] : 0;
#pragma unroll
    for (int m = 1; m < 64; m <<= 1) v += __shfl_xor(v, m, 64);
    __shared__ int ws[16];
    int wave = threadIdx.x >> 6, lane = threadIdx.x & 63;
    if (lane == 0) ws[wave] = v;
    __syncthreads();
    if (threadIdx.x == 0) {
        int s = 0;
#pragma unroll
        for (int k = 0; k < 16; ++k) s += ws[k];
        bsum[blockIdx.x] = s;
    }
}

__global__ void chunk_scan_kernel(const int* __restrict__ bsum, int* __restrict__ bbase,
                                  int nb, int* __restrict__ offsets, int n, int E) {
    int lane = threadIdx.x;  // 64
    int v = (lane < nb) ? bsum[lane] : 0;
    int s = v;
#pragma unroll
    for (int m = 1; m < 64; m <<= 1) {
        int t = __shfl_up(s, m, 64);
        if (lane >= m) s += t;
    }
    if (lane < nb) bbase[lane] = s - v;
    if (lane == 0) offsets[n] = E;
}

__global__ void scan_apply_kernel(const int* __restrict__ deg, const int* __restrict__ bbase,
                                  int* __restrict__ offsets, int* __restrict__ cursor, int n) {
    int i = blockIdx.x * 1024 + threadIdx.x;
    int lane = threadIdx.x & 63, wave = threadIdx.x >> 6;
    int v = (i < n) ? deg[i] : 0;
    int s = v;
#pragma unroll
    for (int m = 1; m < 64; m <<= 1) {
        int t = __shfl_up(s, m, 64);
        if (lane >= m) s += t;
    }
    __shared__ int ws[16];
    if (lane == 63) ws[wave] = s;
    __syncthreads();
    if (wave == 0 && lane < 16) {
        int wv = ws[lane];
        int ss = wv;
#pragma unroll
        for (int m = 1; m < 16; m <<= 1) {
            int t = __shfl_up(ss, m, 64);
            if (lane >= m) ss += t;
        }
        ws[lane] = ss - wv;
    }
    __syncthreads();
    int excl = (s - v) + ws[wave] + bbase[blockIdx.x];
    if (i < n) { offsets[i] = excl; cursor[i] = excl; }
}

__global__ void scatter_kernel(const int* __restrict__ src, const int* __restrict__ dst,
                               int* __restrict__ cursor, int* __restrict__ sorted_src, int E) {
    int e = blockIdx.x * blockDim.x + threadIdx.x;
    if (e < E) {
        int d = dst[e];
        int pos = atomicAdd(&cursor[d], 1);
        sorted_src[pos] = src[e];
    }
}

__global__ void bounds_kernel(const int* __restrict__ batch, int* __restrict__ gstart,
                              int N, int G) {
    int g = blockIdx.x * blockDim.x + threadIdx.x;
    if (g <= G) {
        int lo = 0, hi = N;
        while (lo < hi) {
            int mid = (lo + hi) >> 1;
            if (batch[mid] < g) lo = mid + 1; else hi = mid;
        }
        gstart[g] = lo;
    }
}

__global__ void cvt_kernel(const float4* __restrict__ in, ushort4* __restrict__ out, int n4) {
    int i = blockIdx.x * blockDim.x + threadIdx.x;
    if (i < n4) {
        float4 f = in[i];
        ushort4 o; o.x = f2bf(f.x); o.y = f2bf(f.y); o.z = f2bf(f.z); o.w = f2bf(f.w);
        out[i] = o;
    }
}

// all 4 layers' Wcat in one launch: idx = l*32768 + j*256 + k
__global__ void build_wcat_all(const float* __restrict__ Wr0, const float* __restrict__ Wn0,
                               const float* __restrict__ Wr1, const float* __restrict__ Wn1,
                               const float* __restrict__ Wr2, const float* __restrict__ Wn2,
                               const float* __restrict__ Wr3, const float* __restrict__ Wn3,
                               __hip_bfloat16* __restrict__ wcat) {  // [4][128][256]
    int idx = blockIdx.x * blockDim.x + threadIdx.x;
    if (idx >= 4 * 128 * 256) return;
    int l = idx >> 15;
    int j = (idx >> 8) & 127, k = idx & 255;
    const float* Wr = (l == 0) ? Wr0 : (l == 1) ? Wr1 : (l == 2) ? Wr2 : Wr3;
    const float* Wn = (l == 0) ? Wn0 : (l == 1) ? Wn1 : (l == 2) ? Wn2 : Wn3;
    float v = (k < 128) ? Wr[j * 128 + k] : Wn[j * 128 + (k - 128)];
    wcat[idx] = __float2bfloat16(v);
}

// ---------------- fused per-layer kernel ----------------
// Block = 8 waves (512 thr) owns 64 output rows.
// Phase 1: each wave aggregates 8 nodes' neighbor rows into LDS (row-major,
//          264B padded stride -> read-slot stagger, ~4-way floor on b128).
// Phase 2: wave = colgroup (16 cols); B-frags register-resident; A = h from
//          global (shared across waves via L1) | agg from LDS.
#define LDS_STRIDE 264
__global__ __launch_bounds__(512, 4)
void layer_kernel(const __hip_bfloat16* __restrict__ h,
                  const int* __restrict__ offsets,
                  const int* __restrict__ sorted_src,
                  const __hip_bfloat16* __restrict__ Wcat,  // [128][256]
                  const float* __restrict__ bias,           // [128]
                  __hip_bfloat16* __restrict__ out, int N) {
    __shared__ char lds[64 * LDS_STRIDE];
    int wave = threadIdx.x >> 6;
    int lane = threadIdx.x & 63;
    int row0 = blockIdx.x * 64;
    int half = lane >> 5, fl = lane & 31;
    const uint2* hu = (const uint2*)h;

    // ---- phase 1: aggregate ----
#pragma unroll 1
    for (int i = 0; i < 8; ++i) {
        int lr = wave * 8 + i;
        int node = row0 + lr;
        if (node < N) {
            int s = offsets[node], e = offsets[node + 1];
            f32x4 A0 = {0,0,0,0}, A1 = {0,0,0,0}, A2 = {0,0,0,0}, A3 = {0,0,0,0};
            int t = s;
            for (; t + 8 <= e; t += 8) {
                int j0 = sorted_src[t + half];
                int j1 = sorted_src[t + 2 + half];
                int j2 = sorted_src[t + 4 + half];
                int j3 = sorted_src[t + 6 + half];
                uint2 v0 = hu[(size_t)j0 * 32 + fl];
                uint2 v1 = hu[(size_t)j1 * 32 + fl];
                uint2 v2 = hu[(size_t)j2 * 32 + fl];
                uint2 v3 = hu[(size_t)j3 * 32 + fl];
                A0[0] += blo(v0.x); A0[1] += bhi(v0.x); A0[2] += blo(v0.y); A0[3] += bhi(v0.y);
                A1[0] += blo(v1.x); A1[1] += bhi(v1.x); A1[2] += blo(v1.y); A1[3] += bhi(v1.y);
                A2[0] += blo(v2.x); A2[1] += bhi(v2.x); A2[2] += blo(v2.y); A2[3] += bhi(v2.y);
                A3[0] += blo(v3.x); A3[1] += bhi(v3.x); A3[2] += blo(v3.y); A3[3] += bhi(v3.y);
            }
            if (t + 4 <= e) {
                int j0 = sorted_src[t + half];
                int j1 = sorted_src[t + 2 + half];
                uint2 v0 = hu[(size_t)j0 * 32 + fl];
                uint2 v1 = hu[(size_t)j1 * 32 + fl];
                A0[0] += blo(v0.x); A0[1] += bhi(v0.x); A0[2] += blo(v0.y); A0[3] += bhi(v0.y);
                A1[0] += blo(v1.x); A1[1] += bhi(v1.x); A1[2] += blo(v1.y); A1[3] += bhi(v1.y);
                t += 4;
            }
            if (t + 2 <= e) {
                int j0 = sorted_src[t + half];
                uint2 v0 = hu[(size_t)j0 * 32 + fl];
                A0[0] += blo(v0.x); A0[1] += bhi(v0.x); A0[2] += blo(v0.y); A0[3] += bhi(v0.y);
                t += 2;
            }
            if (t < e && half == 0) {   // odd tail: lo-half only
                int j = sorted_src[t];
                uint2 v = hu[(size_t)j * 32 + fl];
                A1[0] += blo(v.x); A1[1] += bhi(v.x); A1[2] += blo(v.y); A1[3] += bhi(v.y);
            }
            float q0 = (A0[0] + A1[0]) + (A2[0] + A3[0]); q0 += __shfl_xor(q0, 32, 64);
            float q1 = (A0[1] + A1[1]) + (A2[1] + A3[1]); q1 += __shfl_xor(q1, 32, 64);
            float q2 = (A0[2] + A1[2]) + (A2[2] + A3[2]); q2 += __shfl_xor(q2, 32, 64);
            float q3 = (A0[3] + A1[3]) + (A2[3] + A3[3]); q3 += __shfl_xor(q3, 32, 64);
            if (half == 0) {
                ushort4 o; o.x = f2bf(q0); o.y = f2bf(q1); o.z = f2bf(q2); o.w = f2bf(q3);
                *reinterpret_cast<ushort4*>(&lds[lr * LDS_STRIDE + fl * 8]) = o;
            }
        }
    }
    __syncthreads();

    // ---- phase 2: gemm ----
    int la  = lane & 15;
    int keg = lane >> 4;
    int ke0 = keg * 8;
    int col = wave * 16 + la;

    bf16x8 b[8];
#pragma unroll
    for (int ks = 0; ks < 8; ++ks)
        b[ks] = *reinterpret_cast<const bf16x8*>(&Wcat[(size_t)col * 256 + ks * 32 + ke0]);
    float bv = bias[col];

    f32x4 acc[4];
#pragma unroll
    for (int m = 0; m < 4; ++m) {
        int r = row0 + m * 16 + la;
        if (r >= N) r = N - 1;
        const __hip_bfloat16* hr = &h[(size_t)r * 128];
        bf16x8 a[8];
#pragma unroll
        for (int ks = 0; ks < 4; ++ks)
            a[ks] = *reinterpret_cast<const bf16x8*>(&hr[ks * 32 + ke0]);
#pragma unroll
        for (int ks = 0; ks < 4; ++ks)
            a[ks + 4] = *reinterpret_cast<const bf16x8*>(
                &lds[(m * 16 + la) * LDS_STRIDE + ks * 64 + keg * 16]);
        f32x4 c = {0, 0, 0, 0};
#pragma unroll
        for (int ks = 0; ks < 8; ++ks)
            c = __builtin_amdgcn_mfma_f32_16x16x32_bf16(a[ks], b[ks], c, 0, 0, 0);
        acc[m] = c;
    }

    int r0 = row0 + (lane >> 4) * 4;
#pragma unroll
    for (int m = 0; m < 4; ++m) {
#pragma unroll
        for (int j = 0; j < 4; ++j) {
            int r = r0 + m * 16 + j;
            if (r < N)
                out[(size_t)r * 128 + col] = __float2bfloat16(gelu_f(acc[m][j] + bv));
        }
    }
}

// ---------------- pooling ----------------

__global__ void pool_partial(const __hip_bfloat16* __restrict__ h,
                             const int* __restrict__ batch,
                             const float* __restrict__ Wout,
                             float* __restrict__ outsum, int N) {
    int wid = blockIdx.x * 4 + (threadIdx.x >> 6);
    int lane = threadIdx.x & 63;
    int i0 = wid * 16;
    if (i0 >= N) return;
    int half = lane >> 5, fl = lane & 31;
    const uint2* hu = (const uint2*)h;
    float w0 = Wout[4 * fl], w1 = Wout[4 * fl + 1];
    float w2 = Wout[4 * fl + 2], w3 = Wout[4 * fl + 3];
    float dot = 0.f;
    int cur = -1;
#pragma unroll
    for (int t = 0; t < 8; ++t) {
        int i = i0 + 2 * t + half;
        if (i < N) {
            int g = batch[i];
            uint2 v = hu[(size_t)i * 32 + fl];
            float d = blo(v.x) * w0 + bhi(v.x) * w1 + blo(v.y) * w2 + bhi(v.y) * w3;
            if (g != cur) {
                if (cur >= 0) {
                    float r = dot;
#pragma unroll
                    for (int m = 16; m >= 1; m >>= 1) r += __shfl_xor(r, m, 64);
                    if (fl == 0) atomicAdd(&outsum[cur], r);
                }
                cur = g; dot = d;
            } else {
                dot += d;
            }
        }
    }
    if (cur >= 0) {
        float r = dot;
#pragma unroll
        for (int m = 16; m >= 1; m >>= 1) r += __shfl_xor(r, m, 64);
        if (fl == 0) atomicAdd(&outsum[cur], r);
    }
}

__global__ void pool_finish(const float* __restrict__ outsum,
                            const int* __restrict__ gstart,
                            const float* __restrict__ bout,
                            float* __restrict__ out, int G) {
    int g = blockIdx.x * blockDim.x + threadIdx.x;
    if (g < G) {
        float cnt = (float)(gstart[g + 1] - gstart[g]);
        out[g] = outsum[g] / fmaxf(cnt, 1.0f) + bout[0];
    }
}

// ---------------- launch ----------------

extern "C" void kernel_launch(void* const* d_in, const int* in_sizes, int n_in,
                              void* d_out, int out_size, void* d_ws, size_t ws_size,
                              hipStream_t stream) {
    const float* x          = (const float*)d_in[0];
    const int*   edge_index = (const int*)d_in[1];
    const int*   batch      = (const int*)d_in[2];
    const float* Wroot[4] = {(const float*)d_in[3], (const float*)d_in[6],
                             (const float*)d_in[9], (const float*)d_in[12]};
    const float* Wrel[4]  = {(const float*)d_in[4], (const float*)d_in[7],
                             (const float*)d_in[10], (const float*)d_in[13]};
    const float* bias[4]  = {(const float*)d_in[5], (const float*)d_in[8],
                             (const float*)d_in[11], (const float*)d_in[14]};
    const float* Wout = (const float*)d_in[15];
    const float* bout = (const float*)d_in[16];
    float* out = (float*)d_out;

    const int N = in_sizes[2];       // 40000
    const int E = in_sizes[1] / 2;   // 640000
    const int G = 128;
    const int* src = edge_index;
    const int* dst = edge_index + E;

    char* ws = (char*)d_ws;
    size_t o = 0;
    auto alloc = [&](size_t bytes) { void* p = ws + o; o += (bytes + 255) & ~(size_t)255; return p; };

    __hip_bfloat16* hx   = (__hip_bfloat16*)alloc((size_t)N * 128 * 2);
    __hip_bfloat16* hb0  = (__hip_bfloat16*)alloc((size_t)N * 128 * 2);
    __hip_bfloat16* hb1  = (__hip_bfloat16*)alloc((size_t)N * 128 * 2);
    __hip_bfloat16* wcat = (__hip_bfloat16*)alloc((size_t)4 * 128 * 256 * 2);
    int* deg     = (int*)alloc((size_t)N * 4);
    int* offsets = (int*)alloc((size_t)(N + 1) * 4);
    int* cursor  = (int*)alloc((size_t)N * 4);
    int* sorted  = (int*)alloc((size_t)E * 4);
    int* gstart  = (int*)alloc((size_t)(G + 1) * 4);
    int* bsum    = (int*)alloc(64 * 4);
    int* bbase   = (int*)alloc(64 * 4);
    float* outsum = (float*)alloc((size_t)G * 4);

    const int nb = (N + 1023) / 1024;   // 40 (<=64 required by chunk_scan)

    // CSR build (reused by all 4 layers)
    hipMemsetAsync(deg, 0, (size_t)N * 4, stream);
    degree_kernel<<<(E + 255) / 256, 256, 0, stream>>>(dst, deg, E);
    chunk_sum_kernel<<<nb, 1024, 0, stream>>>(deg, bsum, N);
    chunk_scan_kernel<<<1, 64, 0, stream>>>(bsum, bbase, nb, offsets, N, E);
    scan_apply_kernel<<<nb, 1024, 0, stream>>>(deg, bbase, offsets, cursor, N);
    scatter_kernel<<<(E + 255) / 256, 256, 0, stream>>>(src, dst, cursor, sorted, E);
    bounds_kernel<<<1, 256, 0, stream>>>(batch, gstart, N, G);

    // input & weight conversion to bf16
    cvt_kernel<<<(N * 128 / 4 + 255) / 256, 256, 0, stream>>>(
        (const float4*)x, (ushort4*)hx, N * 128 / 4);
    build_wcat_all<<<(4 * 128 * 256 + 255) / 256, 256, 0, stream>>>(
        Wroot[0], Wrel[0], Wroot[1], Wrel[1], Wroot[2], Wrel[2], Wroot[3], Wrel[3], wcat);

    // 4 fused GraphConv + gelu layers
    __hip_bfloat16* hin = hx;
    __hip_bfloat16* houts[4] = {hb0, hb1, hb0, hb1};
    for (int l = 0; l < 4; ++l) {
        layer_kernel<<<(N + 63) / 64, 512, 0, stream>>>(
            hin, offsets, sorted, wcat + (size_t)l * 128 * 256, bias[l], houts[l], N);
        hin = houts[l];
    }

    // fused mean pool + output head
    hipMemsetAsync(outsum, 0, (size_t)G * 4, stream);
    pool_partial<<<((N + 15) / 16 + 3) / 4, 256, 0, stream>>>(hin, batch, Wout, outsum, N);
    pool_finish<<<1, 128, 0, stream>>>(outsum, gstart, bout, out, G);
}